// Round 1
// baseline (156.809 us; speedup 1.0000x reference)
//
#include <hip/hip_runtime.h>

#define BATCH 32
#define NN 4096
#define DD 256
#define KK 32
#define PP 32            // row partitions in k0
#define SS 32            // blocks per batch in k3

typedef __attribute__((ext_vector_type(8))) short bf16x8;
typedef __attribute__((ext_vector_type(4))) float f32x4;

__device__ __forceinline__ unsigned short f2bf(float x) {
  unsigned int u = __float_as_uint(x);
  u += 0x7fffu + ((u >> 16) & 1u);   // round-to-nearest-even
  return (unsigned short)(u >> 16);
}

// ws layout (float offsets)
#define WS_PART   0          // 32*32*256 = 262144 (dead after k1)
#define WS_SMPART 0          // 5*32*32*128 = 655360 (reuses part region, written by k3)
#define WS_MEANS  655360     // 8192
#define WS_WCOMB  663552     // 65536
#define WS_KP     729088     // 262144 (LayerNorm applied in-place)
#define WS_G      991232     // 131072 floats = 262144 bf16

// ---------------- k0: partial column sums of h ----------------
__global__ void k0_partial(const float* __restrict__ h, float* __restrict__ part) {
  int p = blockIdx.x, b = blockIdx.y;
  int t = threadIdx.x;
  int c4 = t & 63, rg = t >> 6;
  const float4* hp = (const float4*)h + (size_t)(b * NN + p * 128) * 64 + c4;
  float4 acc = {0.f, 0.f, 0.f, 0.f};
  for (int r = rg; r < 128; r += 4) {
    float4 v = hp[(size_t)r * 64];
    acc.x += v.x; acc.y += v.y; acc.z += v.z; acc.w += v.w;
  }
  __shared__ float4 sm[256];
  sm[t] = acc;
  __syncthreads();
  if (t < 64) {
    float4 a = sm[t], b2 = sm[t + 64], c = sm[t + 128], d = sm[t + 192];
    float4 tot = {a.x + b2.x + c.x + d.x, a.y + b2.y + c.y + d.y,
                  a.z + b2.z + c.z + d.z, a.w + b2.w + c.w + d.w};
    ((float4*)part)[(size_t)(b * PP + p) * 64 + t] = tot;
  }
}

// ---------------- k1: finish means + W_comb = W_dst^T @ W_src ----------------
__global__ void k1_mean_wcomb(const float* __restrict__ part,
                              const float* __restrict__ Wsrc,
                              const float* __restrict__ Wdst,
                              float* __restrict__ means,
                              float* __restrict__ wcomb) {
  int bid = blockIdx.x, t = threadIdx.x;
  if (bid < 256) {
    int dp = bid;
    float acc = 0.f;
#pragma unroll 4
    for (int e = 0; e < 256; e++) acc += Wdst[e * 256 + dp] * Wsrc[e * 256 + t];
    wcomb[dp * 256 + t] = acc;
  } else {
    int b = bid - 256;
    float s = 0.f;
    for (int p = 0; p < PP; p++) s += part[(size_t)(b * PP + p) * 256 + t];
    means[b * 256 + t] = s * (1.0f / NN);
  }
}

// ---------------- k2a: kp = silu(mean @ W_kp^T + b_kp) ----------------
__global__ void k2a_kp(const float* __restrict__ means, const float* __restrict__ Wkp,
                       const float* __restrict__ bkp, float* __restrict__ kp) {
  int jt = blockIdx.x;   // 0..31
  int bg = blockIdx.y;   // 0..7
  int t = threadIdx.x;
  int j = jt * 256 + t;
  int b0 = bg * 4;
  const float4* wp = (const float4*)Wkp + (size_t)j * 64;
  float acc[4] = {0.f, 0.f, 0.f, 0.f};
  for (int d4 = 0; d4 < 64; d4++) {
    float4 w = wp[d4];
#pragma unroll
    for (int i = 0; i < 4; i++) {
      float4 m = ((const float4*)(means + (size_t)(b0 + i) * 256))[d4];  // uniform -> s_load
      acc[i] += m.x * w.x + m.y * w.y + m.z * w.z + m.w * w.w;
    }
  }
  float bb = bkp[j];
#pragma unroll
  for (int i = 0; i < 4; i++) {
    float x = acc[i] + bb;
    float s = x / (1.0f + __expf(-x));
    kp[(size_t)(b0 + i) * 8192 + j] = s;
  }
}

// ---------------- k2b: LayerNorm over 8192, in place ----------------
__global__ void k2b_ln(float* __restrict__ kp, const float* __restrict__ gamma,
                       const float* __restrict__ beta) {
  int b = blockIdx.x, t = threadIdx.x;
  float v[8];
  float s = 0.f, sq = 0.f;
#pragma unroll
  for (int i = 0; i < 8; i++) {
    v[i] = kp[(size_t)b * 8192 + t + i * 1024];
    s += v[i]; sq += v[i] * v[i];
  }
#pragma unroll
  for (int o = 1; o < 64; o <<= 1) { s += __shfl_xor(s, o); sq += __shfl_xor(sq, o); }
  __shared__ float ss[16], ssq[16];
  int w = t >> 6, lane = t & 63;
  if (lane == 0) { ss[w] = s; ssq[w] = sq; }
  __syncthreads();
  if (t == 0) {
    float a = 0.f, a2 = 0.f;
    for (int i = 0; i < 16; i++) { a += ss[i]; a2 += ssq[i]; }
    ss[0] = a; ssq[0] = a2;
  }
  __syncthreads();
  float mu = ss[0] * (1.0f / 8192.0f);
  float var = ssq[0] * (1.0f / 8192.0f) - mu * mu;
  var = fmaxf(var, 0.f);
  float rs = rsqrtf(var + 1e-5f);
#pragma unroll
  for (int i = 0; i < 8; i++) {
    int j = t + i * 1024;
    kp[(size_t)b * 8192 + j] = (v[i] - mu) * rs * gamma[j] + beta[j];
  }
}

// ---------------- k2c: g = (kp_norm @ W_comb) / 16, cast bf16 ----------------
__global__ void k2c_g(const float* __restrict__ kpn, const float* __restrict__ wcomb,
                      unsigned short* __restrict__ g) {
  int dc = blockIdx.x, b = blockIdx.y, t = threadIdx.x;
  int d = dc * 64 + (t & 63);
  int kb = t >> 6;
  float acc[8] = {0.f, 0.f, 0.f, 0.f, 0.f, 0.f, 0.f, 0.f};
  for (int dp4 = 0; dp4 < 64; dp4++) {
    float w0 = wcomb[(dp4 * 4 + 0) * 256 + d];
    float w1 = wcomb[(dp4 * 4 + 1) * 256 + d];
    float w2 = wcomb[(dp4 * 4 + 2) * 256 + d];
    float w3 = wcomb[(dp4 * 4 + 3) * 256 + d];
#pragma unroll
    for (int i = 0; i < 8; i++) {
      int k = kb + i * 4;
      float4 kv = ((const float4*)(kpn + (size_t)b * 8192 + k * 256))[dp4];  // uniform -> s_load
      acc[i] += kv.x * w0 + kv.y * w1 + kv.z * w2 + kv.w * w3;
    }
  }
#pragma unroll
  for (int i = 0; i < 8; i++) {
    int k = kb + i * 4;
    g[(size_t)(b * KK + k) * 256 + d] = f2bf(acc[i] * 0.0625f);  // fold 1/sqrt(256)
  }
}

// ---------------- k3: scores + online softmax + weighted pos (per-block partials) ----------------
__global__ __launch_bounds__(256, 4) void k3_attn(const float* __restrict__ h,
                                                  const float* __restrict__ pos,
                                                  const unsigned short* __restrict__ g,
                                                  float* __restrict__ smp) {
  int s = blockIdx.x, b = blockIdx.y;
  int t = threadIdx.x;
  int lane = t & 63, w = t >> 6;
  int l15 = lane & 15, l4 = lane >> 4;
  const float LOG2E = 1.4426950408889634f;

  // hoist g fragments into registers (B operand): lane holds g[k=kt*16+l15][kd*32+l4*8 ..+7]
  const unsigned short* gb = g + (size_t)b * 8192;
  bf16x8 gf0[8], gf1[8];
#pragma unroll
  for (int kd = 0; kd < 8; kd++) {
    gf0[kd] = *(const bf16x8*)(gb + ((size_t)l15 << 8) + kd * 32 + (l4 << 3));
    gf1[kd] = *(const bf16x8*)(gb + ((size_t)(16 + l15) << 8) + kd * 32 + (l4 << 3));
  }

  float m0 = -3.0e38f, m1 = -3.0e38f;
  float L0 = 0.f, L1 = 0.f;
  float P0x = 0.f, P0y = 0.f, P0z = 0.f, P1x = 0.f, P1y = 0.f, P1z = 0.f;

  for (int tile = 0; tile < 2; tile++) {
    int nbase = s * 128 + tile * 64 + w * 16;
    int rowA = nbase + l15;
    const float4* hp = (const float4*)(h + ((size_t)(b * NN + rowA) << 8));
    int co = l4 * 2;
    f32x4 acc0 = {0.f, 0.f, 0.f, 0.f}, acc1 = {0.f, 0.f, 0.f, 0.f};
#pragma unroll
    for (int kd = 0; kd < 8; kd++) {
      float4 v0 = hp[kd * 8 + co];
      float4 v1 = hp[kd * 8 + co + 1];
      bf16x8 a;
      a[0] = (short)f2bf(v0.x); a[1] = (short)f2bf(v0.y);
      a[2] = (short)f2bf(v0.z); a[3] = (short)f2bf(v0.w);
      a[4] = (short)f2bf(v1.x); a[5] = (short)f2bf(v1.y);
      a[6] = (short)f2bf(v1.z); a[7] = (short)f2bf(v1.w);
      acc0 = __builtin_amdgcn_mfma_f32_16x16x32_bf16(a, gf0[kd], acc0, 0, 0, 0);
      acc1 = __builtin_amdgcn_mfma_f32_16x16x32_bf16(a, gf1[kd], acc1, 0, 0, 0);
    }
    // pos for this lane's 4 rows (shared by both k-tiles)
    float px[4], py[4], pz[4];
#pragma unroll
    for (int j = 0; j < 4; j++) {
      const float* pp = pos + (size_t)(b * NN + nbase + l4 * 4 + j) * 3;
      px[j] = pp[0]; py[j] = pp[1]; pz[j] = pp[2];
    }
    // online softmax update, k-tile 0
    {
      float tm = fmaxf(fmaxf(acc0[0], acc0[1]), fmaxf(acc0[2], acc0[3]));
      tm = fmaxf(tm, __shfl_xor(tm, 16));
      tm = fmaxf(tm, __shfl_xor(tm, 32));
      float mn = fmaxf(m0, tm);
      float corr = exp2f((m0 - mn) * LOG2E);
      float e0 = exp2f((acc0[0] - mn) * LOG2E);
      float e1 = exp2f((acc0[1] - mn) * LOG2E);
      float e2 = exp2f((acc0[2] - mn) * LOG2E);
      float e3 = exp2f((acc0[3] - mn) * LOG2E);
      float se = e0 + e1 + e2 + e3;
      float sx = e0 * px[0] + e1 * px[1] + e2 * px[2] + e3 * px[3];
      float sy = e0 * py[0] + e1 * py[1] + e2 * py[2] + e3 * py[3];
      float sz = e0 * pz[0] + e1 * pz[1] + e2 * pz[2] + e3 * pz[3];
      se += __shfl_xor(se, 16); se += __shfl_xor(se, 32);
      sx += __shfl_xor(sx, 16); sx += __shfl_xor(sx, 32);
      sy += __shfl_xor(sy, 16); sy += __shfl_xor(sy, 32);
      sz += __shfl_xor(sz, 16); sz += __shfl_xor(sz, 32);
      L0 = L0 * corr + se; P0x = P0x * corr + sx;
      P0y = P0y * corr + sy; P0z = P0z * corr + sz; m0 = mn;
    }
    // online softmax update, k-tile 1
    {
      float tm = fmaxf(fmaxf(acc1[0], acc1[1]), fmaxf(acc1[2], acc1[3]));
      tm = fmaxf(tm, __shfl_xor(tm, 16));
      tm = fmaxf(tm, __shfl_xor(tm, 32));
      float mn = fmaxf(m1, tm);
      float corr = exp2f((m1 - mn) * LOG2E);
      float e0 = exp2f((acc1[0] - mn) * LOG2E);
      float e1 = exp2f((acc1[1] - mn) * LOG2E);
      float e2 = exp2f((acc1[2] - mn) * LOG2E);
      float e3 = exp2f((acc1[3] - mn) * LOG2E);
      float se = e0 + e1 + e2 + e3;
      float sx = e0 * px[0] + e1 * px[1] + e2 * px[2] + e3 * px[3];
      float sy = e0 * py[0] + e1 * py[1] + e2 * py[2] + e3 * py[3];
      float sz = e0 * pz[0] + e1 * pz[1] + e2 * pz[2] + e3 * pz[3];
      se += __shfl_xor(se, 16); se += __shfl_xor(se, 32);
      sx += __shfl_xor(sx, 16); sx += __shfl_xor(sx, 32);
      sy += __shfl_xor(sy, 16); sy += __shfl_xor(sy, 32);
      sz += __shfl_xor(sz, 16); sz += __shfl_xor(sz, 32);
      L1 = L1 * corr + se; P1x = P1x * corr + sx;
      P1y = P1y * corr + sy; P1z = P1z * corr + sz; m1 = mn;
    }
  }
  // lanes 0..31 each hold the complete per-wave state for k = lane
  if (lane < 32) {
    int kt = lane >> 4;
    float mv = kt ? m1 : m0;
    float lv = kt ? L1 : L0;
    float pxv = kt ? P1x : P0x;
    float pyv = kt ? P1y : P0y;
    float pzv = kt ? P1z : P0z;
    size_t base = ((size_t)(b * KK + lane)) * 128 + s * 4 + w;
    smp[base] = mv;
    smp[131072 + base] = lv;
    smp[262144 + base] = pxv;
    smp[393216 + base] = pyv;
    smp[524288 + base] = pzv;
  }
}

// ---------------- k4: combine partials -> kp_pos ----------------
__global__ void k4_final(const float* __restrict__ smp, float* __restrict__ out) {
  int id = blockIdx.x * 256 + threadIdx.x;
  if (id >= BATCH * KK) return;
  const float LOG2E = 1.4426950408889634f;
  size_t base = (size_t)id * 128;
  float M = -3.0e38f;
  for (int j = 0; j < 128; j++) M = fmaxf(M, smp[base + j]);
  float L = 0.f, X = 0.f, Y = 0.f, Z = 0.f;
  for (int j = 0; j < 128; j++) {
    float f = exp2f((smp[base + j] - M) * LOG2E);
    L += smp[131072 + base + j] * f;
    X += smp[262144 + base + j] * f;
    Y += smp[393216 + base + j] * f;
    Z += smp[524288 + base + j] * f;
  }
  float inv = 1.0f / L;
  out[id * 3 + 0] = X * inv;
  out[id * 3 + 1] = Y * inv;
  out[id * 3 + 2] = Z * inv;
}

extern "C" void kernel_launch(void* const* d_in, const int* in_sizes, int n_in,
                              void* d_out, int out_size, void* d_ws, size_t ws_size,
                              hipStream_t stream) {
  const float* h     = (const float*)d_in[0];
  const float* pos   = (const float*)d_in[1];
  const float* Wsrc  = (const float*)d_in[2];
  const float* Wdst  = (const float*)d_in[3];
  const float* Wkp   = (const float*)d_in[4];
  const float* bkp   = (const float*)d_in[5];
  const float* gamma = (const float*)d_in[6];
  const float* beta  = (const float*)d_in[7];
  float* out = (float*)d_out;
  float* ws  = (float*)d_ws;

  hipMemsetAsync(d_out, 0, (size_t)out_size * sizeof(float), stream);

  k0_partial<<<dim3(PP, BATCH), 256, 0, stream>>>(h, ws + WS_PART);
  k1_mean_wcomb<<<288, 256, 0, stream>>>(ws + WS_PART, Wsrc, Wdst,
                                         ws + WS_MEANS, ws + WS_WCOMB);
  k2a_kp<<<dim3(32, 8), 256, 0, stream>>>(ws + WS_MEANS, Wkp, bkp, ws + WS_KP);
  k2b_ln<<<BATCH, 1024, 0, stream>>>(ws + WS_KP, gamma, beta);
  k2c_g<<<dim3(4, BATCH), 256, 0, stream>>>(ws + WS_KP, ws + WS_WCOMB,
                                            (unsigned short*)(ws + WS_G));
  k3_attn<<<dim3(SS, BATCH), 256, 0, stream>>>(h, pos,
                                               (const unsigned short*)(ws + WS_G),
                                               ws + WS_SMPART);
  k4_final<<<4, 256, 0, stream>>>(ws + WS_SMPART, out);
}

// Round 2
// 156.503 us; speedup vs baseline: 1.0020x; 1.0020x over previous
//
#include <hip/hip_runtime.h>

#define BATCH 32
#define NN 4096
#define DD 256
#define KK 32
#define PP 32            // row partitions in k0
#define SS 32            // blocks per batch in k3

typedef __attribute__((ext_vector_type(8))) short bf16x8;
typedef __attribute__((ext_vector_type(4))) float f32x4;

__device__ __forceinline__ unsigned short f2bf(float x) {
  unsigned int u = __float_as_uint(x);
  u += 0x7fffu + ((u >> 16) & 1u);   // round-to-nearest-even
  return (unsigned short)(u >> 16);
}

// ws layout (float offsets)
#define WS_PART   0          // 32*32*256 = 262144 (dead after k1)
#define WS_SMPART 0          // 5*32*32*128 = 655360 (reuses part region, written by k3)
#define WS_MEANS  655360     // 8192
#define WS_WCOMB  663552     // 65536
#define WS_KP     729088     // 262144 (LayerNorm applied in-place)
#define WS_G      991232     // 131072 floats = 262144 bf16

// ---------------- kzero: zero d_out with wide stores (replaces slow runtime fill) ----------------
__global__ void kzero(float4* __restrict__ out, int n4) {
  int i = blockIdx.x * 256 + threadIdx.x;
  if (i < n4) out[i] = float4{0.f, 0.f, 0.f, 0.f};
}

// ---------------- k0: partial column sums of h ----------------
__global__ void k0_partial(const float* __restrict__ h, float* __restrict__ part) {
  int p = blockIdx.x, b = blockIdx.y;
  int t = threadIdx.x;
  int c4 = t & 63, rg = t >> 6;
  const float4* hp = (const float4*)h + (size_t)(b * NN + p * 128) * 64 + c4;
  float4 acc = {0.f, 0.f, 0.f, 0.f};
  for (int r = rg; r < 128; r += 4) {
    float4 v = hp[(size_t)r * 64];
    acc.x += v.x; acc.y += v.y; acc.z += v.z; acc.w += v.w;
  }
  __shared__ float4 sm[256];
  sm[t] = acc;
  __syncthreads();
  if (t < 64) {
    float4 a = sm[t], b2 = sm[t + 64], c = sm[t + 128], d = sm[t + 192];
    float4 tot = {a.x + b2.x + c.x + d.x, a.y + b2.y + c.y + d.y,
                  a.z + b2.z + c.z + d.z, a.w + b2.w + c.w + d.w};
    ((float4*)part)[(size_t)(b * PP + p) * 64 + t] = tot;
  }
}

// ---------------- k1: finish means + W_comb = W_dst^T @ W_src ----------------
__global__ void k1_mean_wcomb(const float* __restrict__ part,
                              const float* __restrict__ Wsrc,
                              const float* __restrict__ Wdst,
                              float* __restrict__ means,
                              float* __restrict__ wcomb) {
  int bid = blockIdx.x, t = threadIdx.x;
  if (bid < 256) {
    int dp = bid;
    float acc = 0.f;
#pragma unroll 4
    for (int e = 0; e < 256; e++) acc += Wdst[e * 256 + dp] * Wsrc[e * 256 + t];
    wcomb[dp * 256 + t] = acc;
  } else {
    int b = bid - 256;
    float s = 0.f;
    for (int p = 0; p < PP; p++) s += part[(size_t)(b * PP + p) * 256 + t];
    means[b * 256 + t] = s * (1.0f / NN);
  }
}

// ---------------- k2a: kp = silu(mean @ W_kp^T + b_kp) ----------------
__global__ void k2a_kp(const float* __restrict__ means, const float* __restrict__ Wkp,
                       const float* __restrict__ bkp, float* __restrict__ kp) {
  int jt = blockIdx.x;   // 0..31
  int bg = blockIdx.y;   // 0..7
  int t = threadIdx.x;
  int j = jt * 256 + t;
  int b0 = bg * 4;
  const float4* wp = (const float4*)Wkp + (size_t)j * 64;
  float acc[4] = {0.f, 0.f, 0.f, 0.f};
  for (int d4 = 0; d4 < 64; d4++) {
    float4 w = wp[d4];
#pragma unroll
    for (int i = 0; i < 4; i++) {
      float4 m = ((const float4*)(means + (size_t)(b0 + i) * 256))[d4];  // uniform -> s_load
      acc[i] += m.x * w.x + m.y * w.y + m.z * w.z + m.w * w.w;
    }
  }
  float bb = bkp[j];
#pragma unroll
  for (int i = 0; i < 4; i++) {
    float x = acc[i] + bb;
    float s = x / (1.0f + __expf(-x));
    kp[(size_t)(b0 + i) * 8192 + j] = s;
  }
}

// ---------------- k2b: LayerNorm over 8192, in place ----------------
__global__ void k2b_ln(float* __restrict__ kp, const float* __restrict__ gamma,
                       const float* __restrict__ beta) {
  int b = blockIdx.x, t = threadIdx.x;
  float v[8];
  float s = 0.f, sq = 0.f;
#pragma unroll
  for (int i = 0; i < 8; i++) {
    v[i] = kp[(size_t)b * 8192 + t + i * 1024];
    s += v[i]; sq += v[i] * v[i];
  }
#pragma unroll
  for (int o = 1; o < 64; o <<= 1) { s += __shfl_xor(s, o); sq += __shfl_xor(sq, o); }
  __shared__ float ss[16], ssq[16];
  int w = t >> 6, lane = t & 63;
  if (lane == 0) { ss[w] = s; ssq[w] = sq; }
  __syncthreads();
  if (t == 0) {
    float a = 0.f, a2 = 0.f;
    for (int i = 0; i < 16; i++) { a += ss[i]; a2 += ssq[i]; }
    ss[0] = a; ssq[0] = a2;
  }
  __syncthreads();
  float mu = ss[0] * (1.0f / 8192.0f);
  float var = ssq[0] * (1.0f / 8192.0f) - mu * mu;
  var = fmaxf(var, 0.f);
  float rs = rsqrtf(var + 1e-5f);
#pragma unroll
  for (int i = 0; i < 8; i++) {
    int j = t + i * 1024;
    kp[(size_t)b * 8192 + j] = (v[i] - mu) * rs * gamma[j] + beta[j];
  }
}

// ---------------- k2c: g = (kp_norm @ W_comb) / 16, cast bf16 ----------------
__global__ void k2c_g(const float* __restrict__ kpn, const float* __restrict__ wcomb,
                      unsigned short* __restrict__ g) {
  int dc = blockIdx.x, b = blockIdx.y, t = threadIdx.x;
  int d = dc * 64 + (t & 63);
  int kb = t >> 6;
  float acc[8] = {0.f, 0.f, 0.f, 0.f, 0.f, 0.f, 0.f, 0.f};
  for (int dp4 = 0; dp4 < 64; dp4++) {
    float w0 = wcomb[(dp4 * 4 + 0) * 256 + d];
    float w1 = wcomb[(dp4 * 4 + 1) * 256 + d];
    float w2 = wcomb[(dp4 * 4 + 2) * 256 + d];
    float w3 = wcomb[(dp4 * 4 + 3) * 256 + d];
#pragma unroll
    for (int i = 0; i < 8; i++) {
      int k = kb + i * 4;
      float4 kv = ((const float4*)(kpn + (size_t)b * 8192 + k * 256))[dp4];  // uniform -> s_load
      acc[i] += kv.x * w0 + kv.y * w1 + kv.z * w2 + kv.w * w3;
    }
  }
#pragma unroll
  for (int i = 0; i < 8; i++) {
    int k = kb + i * 4;
    g[(size_t)(b * KK + k) * 256 + d] = f2bf(acc[i] * 0.0625f);  // fold 1/sqrt(256)
  }
}

// ---------------- k3: scores + online softmax + weighted pos (per-block partials) ----------------
__global__ __launch_bounds__(256, 4) void k3_attn(const float* __restrict__ h,
                                                  const float* __restrict__ pos,
                                                  const unsigned short* __restrict__ g,
                                                  float* __restrict__ smp) {
  int s = blockIdx.x, b = blockIdx.y;
  int t = threadIdx.x;
  int lane = t & 63, w = t >> 6;
  int l15 = lane & 15, l4 = lane >> 4;
  const float LOG2E = 1.4426950408889634f;

  // hoist g fragments into registers (B operand): lane holds g[k=kt*16+l15][kd*32+l4*8 ..+7]
  const unsigned short* gb = g + (size_t)b * 8192;
  bf16x8 gf0[8], gf1[8];
#pragma unroll
  for (int kd = 0; kd < 8; kd++) {
    gf0[kd] = *(const bf16x8*)(gb + ((size_t)l15 << 8) + kd * 32 + (l4 << 3));
    gf1[kd] = *(const bf16x8*)(gb + ((size_t)(16 + l15) << 8) + kd * 32 + (l4 << 3));
  }

  float m0 = -3.0e38f, m1 = -3.0e38f;
  float L0 = 0.f, L1 = 0.f;
  float P0x = 0.f, P0y = 0.f, P0z = 0.f, P1x = 0.f, P1y = 0.f, P1z = 0.f;

  for (int tile = 0; tile < 2; tile++) {
    int nbase = s * 128 + tile * 64 + w * 16;
    int rowA = nbase + l15;
    const float4* hp = (const float4*)(h + ((size_t)(b * NN + rowA) << 8));
    int co = l4 * 2;
    f32x4 acc0 = {0.f, 0.f, 0.f, 0.f}, acc1 = {0.f, 0.f, 0.f, 0.f};
#pragma unroll
    for (int kd = 0; kd < 8; kd++) {
      float4 v0 = hp[kd * 8 + co];
      float4 v1 = hp[kd * 8 + co + 1];
      bf16x8 a;
      a[0] = (short)f2bf(v0.x); a[1] = (short)f2bf(v0.y);
      a[2] = (short)f2bf(v0.z); a[3] = (short)f2bf(v0.w);
      a[4] = (short)f2bf(v1.x); a[5] = (short)f2bf(v1.y);
      a[6] = (short)f2bf(v1.z); a[7] = (short)f2bf(v1.w);
      acc0 = __builtin_amdgcn_mfma_f32_16x16x32_bf16(a, gf0[kd], acc0, 0, 0, 0);
      acc1 = __builtin_amdgcn_mfma_f32_16x16x32_bf16(a, gf1[kd], acc1, 0, 0, 0);
    }
    // pos for this lane's 4 rows (shared by both k-tiles)
    float px[4], py[4], pz[4];
#pragma unroll
    for (int j = 0; j < 4; j++) {
      const float* pp = pos + (size_t)(b * NN + nbase + l4 * 4 + j) * 3;
      px[j] = pp[0]; py[j] = pp[1]; pz[j] = pp[2];
    }
    // online softmax update, k-tile 0
    {
      float tm = fmaxf(fmaxf(acc0[0], acc0[1]), fmaxf(acc0[2], acc0[3]));
      tm = fmaxf(tm, __shfl_xor(tm, 16));
      tm = fmaxf(tm, __shfl_xor(tm, 32));
      float mn = fmaxf(m0, tm);
      float corr = exp2f((m0 - mn) * LOG2E);
      float e0 = exp2f((acc0[0] - mn) * LOG2E);
      float e1 = exp2f((acc0[1] - mn) * LOG2E);
      float e2 = exp2f((acc0[2] - mn) * LOG2E);
      float e3 = exp2f((acc0[3] - mn) * LOG2E);
      float se = e0 + e1 + e2 + e3;
      float sx = e0 * px[0] + e1 * px[1] + e2 * px[2] + e3 * px[3];
      float sy = e0 * py[0] + e1 * py[1] + e2 * py[2] + e3 * py[3];
      float sz = e0 * pz[0] + e1 * pz[1] + e2 * pz[2] + e3 * pz[3];
      se += __shfl_xor(se, 16); se += __shfl_xor(se, 32);
      sx += __shfl_xor(sx, 16); sx += __shfl_xor(sx, 32);
      sy += __shfl_xor(sy, 16); sy += __shfl_xor(sy, 32);
      sz += __shfl_xor(sz, 16); sz += __shfl_xor(sz, 32);
      L0 = L0 * corr + se; P0x = P0x * corr + sx;
      P0y = P0y * corr + sy; P0z = P0z * corr + sz; m0 = mn;
    }
    // online softmax update, k-tile 1
    {
      float tm = fmaxf(fmaxf(acc1[0], acc1[1]), fmaxf(acc1[2], acc1[3]));
      tm = fmaxf(tm, __shfl_xor(tm, 16));
      tm = fmaxf(tm, __shfl_xor(tm, 32));
      float mn = fmaxf(m1, tm);
      float corr = exp2f((m1 - mn) * LOG2E);
      float e0 = exp2f((acc1[0] - mn) * LOG2E);
      float e1 = exp2f((acc1[1] - mn) * LOG2E);
      float e2 = exp2f((acc1[2] - mn) * LOG2E);
      float e3 = exp2f((acc1[3] - mn) * LOG2E);
      float se = e0 + e1 + e2 + e3;
      float sx = e0 * px[0] + e1 * px[1] + e2 * px[2] + e3 * px[3];
      float sy = e0 * py[0] + e1 * py[1] + e2 * py[2] + e3 * py[3];
      float sz = e0 * pz[0] + e1 * pz[1] + e2 * pz[2] + e3 * pz[3];
      se += __shfl_xor(se, 16); se += __shfl_xor(se, 32);
      sx += __shfl_xor(sx, 16); sx += __shfl_xor(sx, 32);
      sy += __shfl_xor(sy, 16); sy += __shfl_xor(sy, 32);
      sz += __shfl_xor(sz, 16); sz += __shfl_xor(sz, 32);
      L1 = L1 * corr + se; P1x = P1x * corr + sx;
      P1y = P1y * corr + sy; P1z = P1z * corr + sz; m1 = mn;
    }
  }
  // lanes 0..31 each hold the complete per-wave state for k = lane
  if (lane < 32) {
    int kt = lane >> 4;
    float mv = kt ? m1 : m0;
    float lv = kt ? L1 : L0;
    float pxv = kt ? P1x : P0x;
    float pyv = kt ? P1y : P0y;
    float pzv = kt ? P1z : P0z;
    size_t base = ((size_t)(b * KK + lane)) * 128 + s * 4 + w;
    smp[base] = mv;
    smp[131072 + base] = lv;
    smp[262144 + base] = pxv;
    smp[393216 + base] = pyv;
    smp[524288 + base] = pzv;
  }
}

// ---------------- k4: combine partials -> kp_pos ----------------
__global__ void k4_final(const float* __restrict__ smp, float* __restrict__ out) {
  int id = blockIdx.x * 256 + threadIdx.x;
  if (id >= BATCH * KK) return;
  const float LOG2E = 1.4426950408889634f;
  size_t base = (size_t)id * 128;
  float M = -3.0e38f;
  for (int j = 0; j < 128; j++) M = fmaxf(M, smp[base + j]);
  float L = 0.f, X = 0.f, Y = 0.f, Z = 0.f;
  for (int j = 0; j < 128; j++) {
    float f = exp2f((smp[base + j] - M) * LOG2E);
    L += smp[131072 + base + j] * f;
    X += smp[262144 + base + j] * f;
    Y += smp[393216 + base + j] * f;
    Z += smp[524288 + base + j] * f;
  }
  float inv = 1.0f / L;
  out[id * 3 + 0] = X * inv;
  out[id * 3 + 1] = Y * inv;
  out[id * 3 + 2] = Z * inv;
}

extern "C" void kernel_launch(void* const* d_in, const int* in_sizes, int n_in,
                              void* d_out, int out_size, void* d_ws, size_t ws_size,
                              hipStream_t stream) {
  const float* h     = (const float*)d_in[0];
  const float* pos   = (const float*)d_in[1];
  const float* Wsrc  = (const float*)d_in[2];
  const float* Wdst  = (const float*)d_in[3];
  const float* Wkp   = (const float*)d_in[4];
  const float* bkp   = (const float*)d_in[5];
  const float* gamma = (const float*)d_in[6];
  const float* beta  = (const float*)d_in[7];
  float* out = (float*)d_out;
  float* ws  = (float*)d_ws;

  int n4 = out_size / 4;                 // out_size = 314368, divisible by 4
  kzero<<<(n4 + 255) / 256, 256, 0, stream>>>((float4*)d_out, n4);

  k0_partial<<<dim3(PP, BATCH), 256, 0, stream>>>(h, ws + WS_PART);
  k1_mean_wcomb<<<288, 256, 0, stream>>>(ws + WS_PART, Wsrc, Wdst,
                                         ws + WS_MEANS, ws + WS_WCOMB);
  k2a_kp<<<dim3(32, 8), 256, 0, stream>>>(ws + WS_MEANS, Wkp, bkp, ws + WS_KP);
  k2b_ln<<<BATCH, 1024, 0, stream>>>(ws + WS_KP, gamma, beta);
  k2c_g<<<dim3(4, BATCH), 256, 0, stream>>>(ws + WS_KP, ws + WS_WCOMB,
                                            (unsigned short*)(ws + WS_G));
  k3_attn<<<dim3(SS, BATCH), 256, 0, stream>>>(h, pos,
                                               (const unsigned short*)(ws + WS_G),
                                               ws + WS_SMPART);
  k4_final<<<4, 256, 0, stream>>>(ws + WS_SMPART, out);
}